// Round 13
// baseline (113.764 us; speedup 1.0000x reference)
//
#include <hip/hip_runtime.h>
#include <hip/hip_bf16.h>

#define BATCH 8
#define NN 2048
#define FIN 128
#define FOUT 64
#define ROWS_TOTAL (BATCH * NN)           // 16384
#define K1_BLOCKS 512                     // projection blocks (dispatched first)
#define K0_BLOCKS 2048                    // mask blocks
#define K0_THREADS (K0_BLOCKS * 256)      // 524288

typedef __attribute__((ext_vector_type(8))) short bf16x8;
typedef __attribute__((ext_vector_type(4))) float f32x4;
typedef __attribute__((ext_vector_type(8))) short short8;

__device__ inline short f2bf(float x) {
    __hip_bfloat16 b = __float2bfloat16(x);   // RNE
    short s;
    __builtin_memcpy(&s, &b, 2);
    return s;
}

// ---------------------------------------------------------------------------
// K01: projection (blocks [0,512)) + adj->bitmask via HIGH-BYTE reads (rest).
// adj values are exactly 0.0f (byte3=0x00) or -1e9f (byte3=0xCE): only byte
// 4i+3 is needed -> 33.5 MB requested instead of 134 MB. Per-lane march keeps
// the validated mask byte layout (byte g = octet g, bit e = adj[8g+e]==0).
// All 64 u8 loads issued before any use (liveness-pinned).
// k1 body byte-identical to validated rounds 1..12.
// ---------------------------------------------------------------------------
__global__ __launch_bounds__(256) void k01(
        const float* __restrict__ h, const float* __restrict__ W,
        const float* __restrict__ a, const float* __restrict__ adj,
        short* __restrict__ whT, float* __restrict__ wh1, float* __restrict__ wh2,
        unsigned char* __restrict__ maskb) {
    const int tid  = threadIdx.x;
    const int lane = tid & 63;
    const int wid  = tid >> 6;

    if (blockIdx.x >= K1_BLOCKS) {
        // ------------ k0: adj high-byte -> bitmask, deep u8 stream ------------
        const int T = (blockIdx.x - K1_BLOCKS) * 256 + tid;   // 0..524287
        const unsigned char* adjb = (const unsigned char*)adj;

        unsigned int x[64];
        #pragma unroll
        for (int it = 0; it < 8; ++it) {
            const unsigned char* p = adjb + 32ull * ((size_t)it * K0_THREADS + T) + 3;
            #pragma unroll
            for (int e = 0; e < 8; ++e)
                x[it * 8 + e] = p[4 * e];      // high byte of adj[8g+e]
        }
        #pragma unroll
        for (int q = 0; q < 8; ++q)
            asm volatile("" ::
                "v"(x[q*8+0]), "v"(x[q*8+1]), "v"(x[q*8+2]), "v"(x[q*8+3]),
                "v"(x[q*8+4]), "v"(x[q*8+5]), "v"(x[q*8+6]), "v"(x[q*8+7]));

        #pragma unroll
        for (int it = 0; it < 8; ++it) {
            const size_t g = (size_t)it * K0_THREADS + T;
            unsigned int by = 0;
            #pragma unroll
            for (int e = 0; e < 8; ++e)
                by |= (x[it * 8 + e] == 0u ? 1u : 0u) << e;
            maskb[g] = (unsigned char)by;
        }
    } else {
        // ---------------- k1: wh = h @ W, whT bf16, wh1/wh2 ----------------
        const int gw   = blockIdx.x * 4 + wid;
        const int row0 = gw * 8;
        const int b    = row0 >> 11;
        const int rloc = row0 & (NN - 1);

        float acc[8] = {0.f,0.f,0.f,0.f,0.f,0.f,0.f,0.f};
        const float* hrow = h + (size_t)row0 * FIN;

        #pragma unroll 2
        for (int kc = 0; kc < FIN / 4; ++kc) {
            float wv0 = W[(4*kc + 0) * FOUT + lane];
            float wv1 = W[(4*kc + 1) * FOUT + lane];
            float wv2 = W[(4*kc + 2) * FOUT + lane];
            float wv3 = W[(4*kc + 3) * FOUT + lane];
            #pragma unroll
            for (int r = 0; r < 8; ++r) {
                float4 h4 = *(const float4*)(hrow + r * FIN + 4*kc);
                acc[r] = fmaf(h4.x, wv0, acc[r]);
                acc[r] = fmaf(h4.y, wv1, acc[r]);
                acc[r] = fmaf(h4.z, wv2, acc[r]);
                acc[r] = fmaf(h4.w, wv3, acc[r]);
            }
        }

        short8 st;
        #pragma unroll
        for (int r = 0; r < 8; ++r) st[r] = f2bf(acc[r]);
        *(short8*)(whT + ((size_t)b * FOUT + lane) * NN + rloc) = st;

        const float a1 = a[lane];
        const float a2 = a[FOUT + lane];
        #pragma unroll
        for (int r = 0; r < 8; ++r) {
            const int row = row0 + r;
            float v1 = acc[r] * a1;
            float v2 = acc[r] * a2;
            #pragma unroll
            for (int m = 32; m >= 1; m >>= 1) {
                v1 += __shfl_xor(v1, m, 64);
                v2 += __shfl_xor(v2, m, 64);
            }
            if (lane == 0) { wh1[row] = v1; wh2[row] = v2; }
        }
    }
}

// ---------------------------------------------------------------------------
// K2 v5 (byte-identical to validated rounds 9..12 core): mask-driven fused
// softmax+PV via MFMA, layout-self-calibrated. No adj stream, no in-loop
// barriers. 16 rows x 8 waves; wave w owns j = cn*256 + w*32 + [0,32).
// ---------------------------------------------------------------------------
__global__ __launch_bounds__(512) void k2_attn(
        const unsigned long long* __restrict__ maskg, const short* __restrict__ whT,
        const float* __restrict__ wh1, const float* __restrict__ wh2,
        float* __restrict__ out) {
    __shared__ unsigned long long lds_mask64[512];   // 4 KB: [16 rows][32 words]
    __shared__ float lds_acc[8][16][FOUT];           // 32 KB
    __shared__ float lds_l[8][16];

    const int tid  = threadIdx.x;
    const int lane = tid & 63;
    const int w    = tid >> 6;               // 0..7
    const int row0 = blockIdx.x * 16;
    const int b    = row0 >> 11;
    const int iloc = lane & 15;
    const int kg   = lane >> 4;              // 0..3

    const float* wh2b = wh2 + b * NN;
    const short* whTb = whT + (size_t)b * FOUT * NN;
    const float  wh1v = wh1[row0 + iloc];

    // mask preload: rows row0..row0+15 = 512 uint64, one per thread
    lds_mask64[tid] = maskg[(size_t)row0 * 32 + tid];

    // --- layout self-calibration (proven round 3) ---
    bf16x8 onesf, idxf;
    #pragma unroll
    for (int e = 0; e < 8; ++e) { onesf[e] = (short)0x3F80; idxf[e] = f2bf((float)iloc); }
    f32x4 rowM = {}, colM = {};
    rowM = __builtin_amdgcn_mfma_f32_16x16x32_bf16(idxf, onesf, rowM, 0, 0, 0);
    colM = __builtin_amdgcn_mfma_f32_16x16x32_bf16(onesf, idxf, colM, 0, 0, 0);
    int rmap[4], cmap[4];
    #pragma unroll
    for (int reg = 0; reg < 4; ++reg) {
        int r = (int)(rowM[reg] * 0.03125f + 0.5f);
        int c = (int)(colM[reg] * 0.03125f + 0.5f);
        rmap[reg] = min(max(r, 0), 15);
        cmap[reg] = min(max(c, 0), 15);
    }

    __syncthreads();   // mask ready
    const unsigned char* mb8 = (const unsigned char*)lds_mask64;

    f32x4 acc[4] = {};
    f32x4 accl = {};

    #pragma unroll 2
    for (int cn = 0; cn < 8; ++cn) {
        const int j0 = cn * 256 + w * 32 + kg * 8;

        // mask byte: bits e=0..7 <-> j0+e  (flat byte = row*256 + j/8)
        const unsigned int mb = mb8[iloc * 256 + cn * 32 + w * 4 + kg];

        float4 w0 = *(const float4*)(wh2b + j0);
        float4 w1 = *(const float4*)(wh2b + j0 + 4);

        bf16x8 bf[4];
        #pragma unroll
        for (int ft = 0; ft < 4; ++ft)
            bf[ft] = *(const bf16x8*)(whTb + (size_t)(ft * 16 + iloc) * NN + j0);

        float pv[8];
        {
            float e, pe;
            e = wh1v + w0.x; pe = __expf(fmaxf(e, 0.2f*e)); pv[0] = (mb & 1u)   ? pe : 0.f;
            e = wh1v + w0.y; pe = __expf(fmaxf(e, 0.2f*e)); pv[1] = (mb & 2u)   ? pe : 0.f;
            e = wh1v + w0.z; pe = __expf(fmaxf(e, 0.2f*e)); pv[2] = (mb & 4u)   ? pe : 0.f;
            e = wh1v + w0.w; pe = __expf(fmaxf(e, 0.2f*e)); pv[3] = (mb & 8u)   ? pe : 0.f;
            e = wh1v + w1.x; pe = __expf(fmaxf(e, 0.2f*e)); pv[4] = (mb & 16u)  ? pe : 0.f;
            e = wh1v + w1.y; pe = __expf(fmaxf(e, 0.2f*e)); pv[5] = (mb & 32u)  ? pe : 0.f;
            e = wh1v + w1.z; pe = __expf(fmaxf(e, 0.2f*e)); pv[6] = (mb & 64u)  ? pe : 0.f;
            e = wh1v + w1.w; pe = __expf(fmaxf(e, 0.2f*e)); pv[7] = (mb & 128u) ? pe : 0.f;
        }
        bf16x8 af;
        #pragma unroll
        for (int e = 0; e < 8; ++e) af[e] = f2bf(pv[e]);

        accl = __builtin_amdgcn_mfma_f32_16x16x32_bf16(af, onesf, accl, 0, 0, 0);
        #pragma unroll
        for (int ft = 0; ft < 4; ++ft)
            acc[ft] = __builtin_amdgcn_mfma_f32_16x16x32_bf16(af, bf[ft], acc[ft], 0, 0, 0);
    }

    // stash partials using the MEASURED layout maps
    #pragma unroll
    for (int ft = 0; ft < 4; ++ft)
        #pragma unroll
        for (int reg = 0; reg < 4; ++reg)
            lds_acc[w][rmap[reg]][ft * 16 + cmap[reg]] = acc[ft][reg];
    #pragma unroll
    for (int reg = 0; reg < 4; ++reg)
        if (cmap[reg] == 0) lds_l[w][rmap[reg]] = accl[reg];
    __syncthreads();

    // combine across 8 waves + normalize + elu; thread -> (f, 2 rows)
    const int f  = tid & 63;
    const int rh = tid >> 6;                 // 0..7
    #pragma unroll
    for (int rr = 0; rr < 2; ++rr) {
        const int r = rh * 2 + rr;
        float s = 0.f, l = 0.f;
        #pragma unroll
        for (int ww = 0; ww < 8; ++ww) {
            s += lds_acc[ww][r][f];
            l += lds_l[ww][r];
        }
        float v = s / l;
        out[(size_t)(row0 + r) * FOUT + f] = (v > 0.f) ? v : (__expf(v) - 1.f);
    }
}

// ---------------------------------------------------------------------------
extern "C" void kernel_launch(void* const* d_in, const int* in_sizes, int n_in,
                              void* d_out, int out_size, void* d_ws, size_t ws_size,
                              hipStream_t stream) {
    const float* h   = (const float*)d_in[0];   // [8,2048,128]
    const float* adj = (const float*)d_in[1];   // [8,2048,2048]
    const float* W   = (const float*)d_in[2];   // [128,64]
    const float* a   = (const float*)d_in[3];   // [128,1]
    float* out = (float*)d_out;                 // [8,2048,64]

    short* whT = (short*)d_ws;                              // 2 MB bf16 [8][64][2048]
    float* wh1 = (float*)(whT + (size_t)BATCH * FOUT * NN); // 64 KB
    float* wh2 = wh1 + ROWS_TOTAL;                          // 64 KB
    unsigned char* maskb = (unsigned char*)(wh2 + ROWS_TOTAL);  // 4 MB

    k01<<<K1_BLOCKS + K0_BLOCKS, 256, 0, stream>>>(h, W, a, adj, whT, wh1, wh2, maskb);
    k2_attn<<<ROWS_TOTAL / 16, 512, 0, stream>>>((const unsigned long long*)maskb,
                                                 whT, wh1, wh2, out);
}

// Round 14
// 70.503 us; speedup vs baseline: 1.6136x; 1.6136x over previous
//
#include <hip/hip_runtime.h>
#include <hip/hip_bf16.h>

#define BATCH 8
#define NN 2048
#define FIN 128
#define FOUT 64
#define ROWS_TOTAL (BATCH * NN)           // 16384
#define JB 256                            // j-tile per staging chunk
#define NCH (NN / JB)                     // 8 chunks

typedef __attribute__((ext_vector_type(8))) short bf16x8;
typedef __attribute__((ext_vector_type(4))) float f32x4;
typedef __attribute__((ext_vector_type(8))) short short8;

__device__ inline short f2bf(float x) {
    __hip_bfloat16 b = __float2bfloat16(x);   // RNE
    short s;
    __builtin_memcpy(&s, &b, 2);
    return s;
}

// scores -> exp -> bf16 A-fragment for one 16x32 tile (8 j per lane)
__device__ inline bf16x8 score8(float q, float4 w0, float4 w1, float4 a0, float4 a1) {
    float p[8];
    float e;
    e = q + w0.x; p[0] = __expf(fmaxf(e, 0.2f * e) + a0.x);
    e = q + w0.y; p[1] = __expf(fmaxf(e, 0.2f * e) + a0.y);
    e = q + w0.z; p[2] = __expf(fmaxf(e, 0.2f * e) + a0.z);
    e = q + w0.w; p[3] = __expf(fmaxf(e, 0.2f * e) + a0.w);
    e = q + w1.x; p[4] = __expf(fmaxf(e, 0.2f * e) + a1.x);
    e = q + w1.y; p[5] = __expf(fmaxf(e, 0.2f * e) + a1.y);
    e = q + w1.z; p[6] = __expf(fmaxf(e, 0.2f * e) + a1.z);
    e = q + w1.w; p[7] = __expf(fmaxf(e, 0.2f * e) + a1.w);
    bf16x8 r;
    #pragma unroll
    for (int i = 0; i < 8; ++i) r[i] = f2bf(p[i]);
    return r;
}

// ---------------------------------------------------------------------------
// K1: wh = h @ W; store whT as bf16 [B][FOUT][NN]; wh1 = wh@a[:64], wh2 = wh@a[64:]
// (unchanged — validated)
// ---------------------------------------------------------------------------
__global__ __launch_bounds__(256) void k1_proj(
        const float* __restrict__ h, const float* __restrict__ W,
        const float* __restrict__ a,
        short* __restrict__ whT, float* __restrict__ wh1, float* __restrict__ wh2) {
    const int tid  = threadIdx.x;
    const int lane = tid & 63;
    const int wid  = tid >> 6;
    const int gw   = blockIdx.x * 4 + wid;
    const int row0 = gw * 8;
    const int b    = row0 >> 11;
    const int rloc = row0 & (NN - 1);

    float acc[8] = {0.f,0.f,0.f,0.f,0.f,0.f,0.f,0.f};
    const float* hrow = h + (size_t)row0 * FIN;

    #pragma unroll 2
    for (int kc = 0; kc < FIN / 4; ++kc) {
        float wv0 = W[(4*kc + 0) * FOUT + lane];
        float wv1 = W[(4*kc + 1) * FOUT + lane];
        float wv2 = W[(4*kc + 2) * FOUT + lane];
        float wv3 = W[(4*kc + 3) * FOUT + lane];
        #pragma unroll
        for (int r = 0; r < 8; ++r) {
            float4 h4 = *(const float4*)(hrow + r * FIN + 4*kc);
            acc[r] = fmaf(h4.x, wv0, acc[r]);
            acc[r] = fmaf(h4.y, wv1, acc[r]);
            acc[r] = fmaf(h4.z, wv2, acc[r]);
            acc[r] = fmaf(h4.w, wv3, acc[r]);
        }
    }

    short8 st;
    #pragma unroll
    for (int r = 0; r < 8; ++r) st[r] = f2bf(acc[r]);
    *(short8*)(whT + ((size_t)b * FOUT + lane) * NN + rloc) = st;

    const float a1 = a[lane];
    const float a2 = a[FOUT + lane];
    #pragma unroll
    for (int r = 0; r < 8; ++r) {
        const int row = row0 + r;
        float v1 = acc[r] * a1;
        float v2 = acc[r] * a2;
        #pragma unroll
        for (int m = 32; m >= 1; m >>= 1) {
            v1 += __shfl_xor(v1, m, 64);
            v2 += __shfl_xor(v2, m, 64);
        }
        if (lane == 0) { wh1[row] = v1; wh2[row] = v2; }
    }
}

// ---------------------------------------------------------------------------
// K2 v4b (best measured, round 7: 70.9us total): adj staged in LDS via
// global_load_lds (width=16, coalesced), double-buffered, XOR-swizzled both
// sides. 16 rows x 8 waves. Layout-self-calibrated MFMA.
// ---------------------------------------------------------------------------
__global__ __launch_bounds__(512) void k2_attn(
        const float* __restrict__ adj, const short* __restrict__ whT,
        const float* __restrict__ wh1, const float* __restrict__ wh2,
        float* __restrict__ out) {
    __shared__ char smem[2 * 16 * JB * 4];   // 32 KB: 2 x [16 rows][256 j] f32
    __shared__ float lds_l[8][16];

    const int tid  = threadIdx.x;
    const int lane = tid & 63;
    const int w    = tid >> 6;               // 0..7
    const int row0 = blockIdx.x * 16;
    const int b    = row0 >> 11;
    const int iloc = lane & 15;
    const int kg   = lane >> 4;              // 0..3

    const float* wh2b = wh2 + b * NN;
    const short* whTb = whT + (size_t)b * FOUT * NN;
    const float  wh1v = wh1[row0 + iloc];

    // --- layout self-calibration (proven round 3) ---
    bf16x8 onesf, idxf;
    #pragma unroll
    for (int e = 0; e < 8; ++e) { onesf[e] = (short)0x3F80; idxf[e] = f2bf((float)iloc); }
    f32x4 rowM = {}, colM = {};
    rowM = __builtin_amdgcn_mfma_f32_16x16x32_bf16(idxf, onesf, rowM, 0, 0, 0);
    colM = __builtin_amdgcn_mfma_f32_16x16x32_bf16(onesf, idxf, colM, 0, 0, 0);
    int rmap[4], cmap[4];
    #pragma unroll
    for (int reg = 0; reg < 4; ++reg) {
        int r = (int)(rowM[reg] * 0.03125f + 0.5f);
        int c = (int)(colM[reg] * 0.03125f + 0.5f);
        rmap[reg] = min(max(r, 0), 15);
        cmap[reg] = min(max(c, 0), 15);
    }

    f32x4 acc[4] = {};
    f32x4 accl = {};

    // staging geometry: slot s = q*512 + tid covers LDS bytes [s*16, s*16+16);
    // row r = s>>6, 16B-chunk c = s&63; source chunk = c ^ (r&7)  (involution).
    const int s0 = tid;          // round 0 slot
    const int s1 = 512 + tid;    // round 1 slot
    const int r0s = s0 >> 6, c0s = s0 & 63;
    const int r1s = s1 >> 6, c1s = s1 & 63;
    const float* src0base = adj + (size_t)(row0 + r0s) * NN + ((c0s ^ (r0s & 7)) << 2);
    const float* src1base = adj + (size_t)(row0 + r1s) * NN + ((c1s ^ (r1s & 7)) << 2);

    #define STAGE(chunk, bufsel)                                                   \
        do {                                                                       \
            char* dst = smem + (bufsel) * (16 * JB * 4);                           \
            __builtin_amdgcn_global_load_lds(                                      \
                (const __attribute__((address_space(1))) unsigned int*)(src0base + (size_t)(chunk) * JB), \
                (__attribute__((address_space(3))) unsigned int*)(dst + s0 * 16),  \
                16, 0, 0);                                                         \
            __builtin_amdgcn_global_load_lds(                                      \
                (const __attribute__((address_space(1))) unsigned int*)(src1base + (size_t)(chunk) * JB), \
                (__attribute__((address_space(3))) unsigned int*)(dst + s1 * 16),  \
                16, 0, 0);                                                         \
        } while (0)

    // reader: wave w, chunk-pair cpr = w*8 + kg*2 within the 64-chunk row
    const int cpr = w * 8 + kg * 2;
    const int swz = iloc & 7;
    const int rd0 = iloc * (JB * 4) + ((cpr ^ swz) << 4);
    const int rd1 = iloc * (JB * 4) + (((cpr + 1) ^ swz) << 4);

    // prologue: stage chunk 0 into buf 0
    STAGE(0, 0);

    for (int cn = 0; cn < NCH; ++cn) {
        __syncthreads();                       // stage(cn) complete; buf[cn^1] free
        if (cn < NCH - 1) STAGE(cn + 1, (cn + 1) & 1);   // in flight under compute

        const char* bufc = smem + (cn & 1) * (16 * JB * 4);
        float4 a0 = *(const float4*)(bufc + rd0);   // adj[iloc][cn*256 + w*32 + kg*8 ..+4)
        float4 a1 = *(const float4*)(bufc + rd1);   // ..+4..+8)

        const int j0 = cn * JB + w * 32 + kg * 8;
        float4 w0 = *(const float4*)(wh2b + j0);
        float4 w1 = *(const float4*)(wh2b + j0 + 4);

        bf16x8 bf[4];
        #pragma unroll
        for (int ft = 0; ft < 4; ++ft)
            bf[ft] = *(const bf16x8*)(whTb + (size_t)(ft * 16 + iloc) * NN + j0);  // incl. kg*8

        bf16x8 af = score8(wh1v, w0, w1, a0, a1);

        accl = __builtin_amdgcn_mfma_f32_16x16x32_bf16(af, onesf, accl, 0, 0, 0);
        #pragma unroll
        for (int ft = 0; ft < 4; ++ft)
            acc[ft] = __builtin_amdgcn_mfma_f32_16x16x32_bf16(af, bf[ft], acc[ft], 0, 0, 0);
    }
    #undef STAGE

    __syncthreads();   // all waves done reading smem -> safe to reuse for epilogue

    // stash partials using the MEASURED layout maps; lds_acc reuses smem (32 KB)
    float* lds_acc = (float*)smem;             // [8][16][FOUT]
    #pragma unroll
    for (int ft = 0; ft < 4; ++ft)
        #pragma unroll
        for (int reg = 0; reg < 4; ++reg)
            lds_acc[(w * 16 + rmap[reg]) * FOUT + ft * 16 + cmap[reg]] = acc[ft][reg];
    #pragma unroll
    for (int reg = 0; reg < 4; ++reg)
        if (cmap[reg] == 0) lds_l[w][rmap[reg]] = accl[reg];
    __syncthreads();

    // combine across 8 waves + normalize + elu; thread -> (f, 2 rows)
    const int f  = tid & 63;
    const int rh = tid >> 6;                   // 0..7
    #pragma unroll
    for (int rr = 0; rr < 2; ++rr) {
        const int r = rh * 2 + rr;
        float s = 0.f, l = 0.f;
        #pragma unroll
        for (int ww = 0; ww < 8; ++ww) {
            s += lds_acc[(ww * 16 + r) * FOUT + f];
            l += lds_l[ww][r];
        }
        float v = s / l;
        out[(size_t)(row0 + r) * FOUT + f] = (v > 0.f) ? v : (__expf(v) - 1.f);
    }
}

// ---------------------------------------------------------------------------
extern "C" void kernel_launch(void* const* d_in, const int* in_sizes, int n_in,
                              void* d_out, int out_size, void* d_ws, size_t ws_size,
                              hipStream_t stream) {
    const float* h   = (const float*)d_in[0];   // [8,2048,128]
    const float* adj = (const float*)d_in[1];   // [8,2048,2048]
    const float* W   = (const float*)d_in[2];   // [128,64]
    const float* a   = (const float*)d_in[3];   // [128,1]
    float* out = (float*)d_out;                 // [8,2048,64]

    short* whT = (short*)d_ws;                             // [8][64][2048] bf16 = 2 MB
    float* wh1 = (float*)(whT + (size_t)BATCH * FOUT * NN);// 16384 f32
    float* wh2 = wh1 + ROWS_TOTAL;                         // 16384 f32

    k1_proj<<<ROWS_TOTAL / 32, 256, 0, stream>>>(h, W, a, whT, wh1, wh2);
    k2_attn<<<ROWS_TOTAL / 16, 512, 0, stream>>>(adj, whT, wh1, wh2, out);
}